// Round 5
// baseline (377.993 us; speedup 1.0000x reference)
//
#include <hip/hip_runtime.h>

// Bilinear warp (grid_sample, zeros padding) of frame_t (8,64,256,256) fp32
// by flow_field (8,2,256,256) fp32.
//   ix = px + 0.5*flow_x ; iy = py + 0.5*flow_y   (normalization collapses)
//
// R8 — R7 diagnosis: weight arrays (80 regs) spilled at VGPR_Count=64, and
// the channel loop exposed staging latency between barriers (VALU 11.5%,
// dur UP vs R5). Fix both, keep the 8x weight amortization:
//  - BAND 16->8: persistent state halves (w00..w11[8]+oidx[8] = 40 regs)
//    -> everything fits under the 128-VGPR cap at 4 blocks/CU. Window =
//    8+2*12 = 32 rows = 32 KiB; grid = 8b x 32band x 8cg = 2048 blocks.
//  - T14 async-STAGE split: loads for window ch+1 issued into 8xfloat4
//    regs BEFORE gather(ch); after the post-gather barrier only the cheap
//    ds_write phase runs between barriers. Global latency hides under the
//    previous gather; no exposed global load in the loop.
//  - Fixup (window misses, |disp_y|>~12, ~0.4%/px) hoisted AFTER the
//    channel loop: taps are global loads anyway, all 8 channels issued
//    together (32-deep MLP) instead of 8 barrier-adjacent stalls.
//  - Edge-remap weights (proven R7): border validity + clamp folded into
//    w00..w11 once; inner loop = 4 ds_read + 4 FMA + 1 nontemporal store.
//  - b in low 3 bits of blockIdx -> XCD-local; band next -> adjacent
//    blocks overlap 24/32 window rows in L2.

#define B_ 8
#define C_ 64
#define H_ 256
#define W_ 256
#define HW_ (H_ * W_)
#define BAND 8
#define NBAND (H_ / BAND)              // 32
#define HALO 12
#define WROWS (BAND + 2 * HALO)        // 32 rows
#define WFLOATS (WROWS * W_)           // 8192 floats = 32 KiB
#define WMAXBR (WROWS - 2)             // 30: max base row (reads brw, brw+1)
#define CG 8                           // channels per block
#define STV (WFLOATS / (256 * 4))      // 8 float4 per thread per window

__global__ __launch_bounds__(256, 4) void warp_bilinear_kernel(
    const float* __restrict__ frame,   // (8,64,256,256)
    const float* __restrict__ flow,    // (8,2,256,256)
    float* __restrict__ out)           // (8,64,256,256)
{
    __shared__ float win[WFLOATS];

    const int blk  = blockIdx.x;
    const int b    = blk & 7;          // XCD-local batch
    const int t    = blk >> 3;
    const int band = t & (NBAND - 1);  // next-fastest: L2 row overlap
    const int cg   = t >> 5;           // 0..7
    const int c0   = cg * CG;

    const int r0  = band * BAND;
    const int wlo = r0 - HALO;         // first window row (may be <0)

    const int tid = threadIdx.x;       // 0..255 == pixel column
    const int px  = tid;

    const size_t bc0 = (size_t)(b * C_ + c0) * HW_;

    // ---- flow loads first (weights need them soonest) ----
    const int spbase = r0 * W_ + px;
    const float* __restrict__ flx = flow + (size_t)(b * 2 + 0) * HW_;
    const float* __restrict__ fly = flow + (size_t)(b * 2 + 1) * HW_;

    float fx[BAND], fy[BAND];
#pragma unroll
    for (int r = 0; r < BAND; ++r) {
        fx[r] = flx[spbase + r * W_];
        fy[r] = fly[spbase + r * W_];
    }

    // ---- per-thread staging offsets (y-clamped = row replication) ----
    int soff[STV];
#pragma unroll
    for (int it = 0; it < STV; ++it) {
        const int lin = it * 1024 + tid * 4;
        const int wr  = lin >> 8;                        // window row
        const int gy  = min(max(wlo + wr, 0), H_ - 1);
        soff[it] = gy * W_ + (lin & 255);
    }

    // ---- issue stage loads for channel 0 (hide under weight compute) ----
    float4 f4[STV];
#pragma unroll
    for (int it = 0; it < STV; ++it)
        f4[it] = *(const float4*)(frame + bc0 + soff[it]);

    // ---- weights + addresses, ONCE for all CG channels (R7-proven) ----
    float w00[BAND], w01[BAND], w10[BAND], w11[BAND];
    int   oidx[BAND];
    unsigned badmask = 0u;

#pragma unroll
    for (int r = 0; r < BAND; ++r) {
        const int py = r0 + r;
        const float ix = (float)px + 0.5f * fx[r];
        const float iy = (float)py + 0.5f * fy[r];

        const float ix0f = floorf(ix);
        const float iy0f = floorf(iy);
        const float wx1 = ix - ix0f;
        const float wx0 = 1.0f - wx1;
        const float wy1 = iy - iy0f;
        const float wy0 = 1.0f - wy1;

        const int ix0 = (int)ix0f;
        const int iy0 = (int)iy0f;

        // x edge-remap onto base=clamp(ix0,0,254): a=col base, b=col base+1
        float ea = wx0, eb = wx1;
        if (ix0 == -1)                { ea = wx1;  eb = 0.0f; }
        if (ix0 == W_ - 1)            { ea = 0.0f; eb = wx0;  }
        if (ix0 < -1 || ix0 > W_ - 1) { ea = 0.0f; eb = 0.0f; }

        // y validity (zeros padding); y clamp via staging row replication
        const float ey0 = ((unsigned)iy0       < (unsigned)H_) ? wy0 : 0.0f;
        const float ey1 = ((unsigned)(iy0 + 1) < (unsigned)H_) ? wy1 : 0.0f;

        w00[r] = ey0 * ea; w01[r] = ey0 * eb;
        w10[r] = ey1 * ea; w11[r] = ey1 * eb;

        const int base = min(max(ix0, 0), W_ - 2);   // 0..254
        const int brw  = iy0 - wlo;
        const int brwc = min(max(brw, 0), WMAXBR);   // 0..30
        badmask |= ((unsigned)brw > (unsigned)WMAXBR) ? (1u << r) : 0u;
        oidx[r] = brwc * W_ + base;
    }

    const bool anybad = __any(badmask != 0u);

    // ---- write window 0; prefetch channel 1 into regs ----
#pragma unroll
    for (int it = 0; it < STV; ++it)
        *(float4*)(win + it * 1024 + tid * 4) = f4[it];
#pragma unroll
    for (int it = 0; it < STV; ++it)
        f4[it] = *(const float4*)(frame + bc0 + HW_ + soff[it]);

    __syncthreads();                   // window 0 staged

    // ---- channel loop: gather(ch) while loads(ch+1) fly ----
#pragma unroll 1
    for (int ch = 0; ch < CG; ++ch) {
        float* __restrict__ dst = out + bc0 + (size_t)ch * HW_ + spbase;

#pragma unroll
        for (int r = 0; r < BAND; ++r) {
            const int o = oidx[r];
            const float a  = win[o];
            const float bb = win[o + 1];
            const float cl = win[o + W_];
            const float dl = win[o + W_ + 1];
            const float v = w00[r] * a + w01[r] * bb + w10[r] * cl + w11[r] * dl;
            __builtin_nontemporal_store(v, dst + r * W_);
        }

        if (ch + 1 < CG) {
            __syncthreads();           // all window reads done
            // ds_write phase (waits vmcnt for f4 only)
#pragma unroll
            for (int it = 0; it < STV; ++it)
                *(float4*)(win + it * 1024 + tid * 4) = f4[it];
            if (ch + 2 < CG) {
                // issue next prefetch; latency spans next gather
#pragma unroll
                for (int it = 0; it < STV; ++it)
                    f4[it] = *(const float4*)(frame + bc0 + (size_t)(ch + 2) * HW_ + soff[it]);
            }
            __syncthreads();           // new window staged
        }
    }

    // ---- hoisted fixup: window-miss rows, global taps, all channels ----
    if (anybad) {
#pragma unroll 1
        for (int r = 0; r < BAND; ++r) {
            if ((badmask >> r) & 1u) {
                const int py = r0 + r;
                const float fxr = flx[spbase + r * W_];   // L2 hit
                const float fyr = fly[spbase + r * W_];

                const float ix = (float)px + 0.5f * fxr;
                const float iy = (float)py + 0.5f * fyr;

                const float ix0f = floorf(ix);
                const float iy0f = floorf(iy);
                const float wx1 = ix - ix0f;
                const float wx0 = 1.0f - wx1;
                const float wy1 = iy - iy0f;
                const float wy0 = 1.0f - wy1;

                const int ix0 = (int)ix0f;
                const int iy0 = (int)iy0f;

                const float wx0v = ((unsigned)ix0       < (unsigned)W_) ? wx0 : 0.0f;
                const float wx1v = ((unsigned)(ix0 + 1) < (unsigned)W_) ? wx1 : 0.0f;
                const float wy0v = ((unsigned)iy0       < (unsigned)H_) ? wy0 : 0.0f;
                const float wy1v = ((unsigned)(iy0 + 1) < (unsigned)H_) ? wy1 : 0.0f;

                const int xc0 = min(max(ix0, 0), W_ - 1);
                const int xc1 = min(max(ix0 + 1, 0), W_ - 1);
                const int yc0 = min(max(iy0, 0), H_ - 1);
                const int yc1 = min(max(iy0 + 1, 0), H_ - 1);

#pragma unroll
                for (int ch = 0; ch < CG; ++ch) {
                    const float* __restrict__ src = frame + bc0 + (size_t)ch * HW_;
                    const float t00 = src[yc0 * W_ + xc0];
                    const float t01 = src[yc0 * W_ + xc1];
                    const float t10 = src[yc1 * W_ + xc0];
                    const float t11 = src[yc1 * W_ + xc1];

                    const float h0 = wx0v * t00 + wx1v * t01;
                    const float h1 = wx0v * t10 + wx1v * t11;
                    const float v  = wy0v * h0 + wy1v * h1;

                    __builtin_nontemporal_store(v, out + bc0 + (size_t)ch * HW_ + spbase + r * W_);
                }
            }
        }
    }
}

extern "C" void kernel_launch(void* const* d_in, const int* in_sizes, int n_in,
                              void* d_out, int out_size, void* d_ws, size_t ws_size,
                              hipStream_t stream) {
    const float* frame = (const float*)d_in[0];
    const float* flow  = (const float*)d_in[1];
    float* out = (float*)d_out;

    dim3 grid(B_ * NBAND * (C_ / CG));  // 2048 blocks: (cg, band, b), b fastest
    dim3 block(256);
    warp_bilinear_kernel<<<grid, block, 0, stream>>>(frame, flow, out);
}

// Round 6
// 368.284 us; speedup vs baseline: 1.0264x; 1.0264x over previous
//
#include <hip/hip_runtime.h>

// Bilinear warp (grid_sample, zeros padding) of frame_t (8,64,256,256) fp32
// by flow_field (8,2,256,256) fp32.
//   ix = px + 0.5*flow_x ; iy = py + 0.5*flow_y   (normalization collapses)
//
// R9 — R8 failed on TWO counts, both visible in counters (WRITE_SIZE 508MB,
// VGPR 52): (1) persistent state + f4 prefetch exceeded the 128-VGPR cap of
// launch_bounds(256,4) -> allocator dumped the arrays to scratch (380MB/
// dispatch of spill traffic); (2) prefetch loads were issued immediately
// before __syncthreads, whose implicit s_waitcnt vmcnt(0) drained them ->
// zero overlap. Fixes:
//  - __launch_bounds__(256,3): VGPR cap ~168, state (~115) fits with
//    headroom. 3 blocks/CU (VGPR-bound; LDS 32KB would allow 5).
//  - Channel pipeline: barrier; ISSUE loads(ch+1); gather(ch); barrier;
//    ds_write. Loads drain one full gather later -> latency hidden; no
//    load is issued adjacent to its draining barrier.
//  - Weight amortization (proven R7/R8 math): w00..w11/oidx computed once
//    per block, reused for 8 channels; edge-remap folds border clamp +
//    zeros padding into the weights; y-clamp via staged-row replication.
//  - Window misses (~0.4%/px worst rows) -> badmask, hoisted global-tap
//    fixup after the channel loop.
//  - b in low 3 bits of blockIdx -> XCD-local; band next -> 24/32-row L2
//    overlap between adjacent blocks.

#define B_ 8
#define C_ 64
#define H_ 256
#define W_ 256
#define HW_ (H_ * W_)
#define BAND 8
#define NBAND (H_ / BAND)              // 32
#define HALO 12
#define WROWS (BAND + 2 * HALO)        // 32 rows
#define WFLOATS (WROWS * W_)           // 8192 floats = 32 KiB
#define WMAXBR (WROWS - 2)             // 30: max base row (reads brw, brw+1)
#define CG 8                           // channels per block
#define STV (WFLOATS / (256 * 4))      // 8 float4 per thread per window

__global__ __launch_bounds__(256, 3) void warp_bilinear_kernel(
    const float* __restrict__ frame,   // (8,64,256,256)
    const float* __restrict__ flow,    // (8,2,256,256)
    float* __restrict__ out)           // (8,64,256,256)
{
    __shared__ float win[WFLOATS];

    const int blk  = blockIdx.x;
    const int b    = blk & 7;          // XCD-local batch
    const int t    = blk >> 3;
    const int band = t & (NBAND - 1);  // next-fastest: L2 row overlap
    const int cg   = t >> 5;           // 0..7
    const int c0   = cg * CG;

    const int r0  = band * BAND;
    const int wlo = r0 - HALO;         // first window row (may be <0)

    const int tid = threadIdx.x;       // 0..255 == pixel column
    const int px  = tid;

    const size_t bc0 = (size_t)(b * C_ + c0) * HW_;

    // ---- per-thread staging offsets (y-clamped = row replication) ----
    int soff[STV];
#pragma unroll
    for (int it = 0; it < STV; ++it) {
        const int lin = it * 1024 + tid * 4;
        const int wr  = lin >> 8;                        // window row
        const int gy  = min(max(wlo + wr, 0), H_ - 1);
        soff[it] = gy * W_ + (lin & 255);
    }

    // ---- issue stage loads for channel 0 (hide under weight compute) ----
    float4 f4[STV];
#pragma unroll
    for (int it = 0; it < STV; ++it)
        f4[it] = *(const float4*)(frame + bc0 + soff[it]);

    // ---- flow for this band ----
    const int spbase = r0 * W_ + px;
    const float* __restrict__ flx = flow + (size_t)(b * 2 + 0) * HW_;
    const float* __restrict__ fly = flow + (size_t)(b * 2 + 1) * HW_;

    float fx[BAND], fy[BAND];
#pragma unroll
    for (int r = 0; r < BAND; ++r) {
        fx[r] = flx[spbase + r * W_];
        fy[r] = fly[spbase + r * W_];
    }

    // ---- weights + addresses, ONCE for all CG channels (R7-proven) ----
    float w00[BAND], w01[BAND], w10[BAND], w11[BAND];
    int   oidx[BAND];
    unsigned badmask = 0u;

#pragma unroll
    for (int r = 0; r < BAND; ++r) {
        const int py = r0 + r;
        const float ix = (float)px + 0.5f * fx[r];
        const float iy = (float)py + 0.5f * fy[r];

        const float ix0f = floorf(ix);
        const float iy0f = floorf(iy);
        const float wx1 = ix - ix0f;
        const float wx0 = 1.0f - wx1;
        const float wy1 = iy - iy0f;
        const float wy0 = 1.0f - wy1;

        const int ix0 = (int)ix0f;
        const int iy0 = (int)iy0f;

        // x edge-remap onto base=clamp(ix0,0,254): a=col base, b=col base+1
        float ea = wx0, eb = wx1;
        if (ix0 == -1)                { ea = wx1;  eb = 0.0f; }
        if (ix0 == W_ - 1)            { ea = 0.0f; eb = wx0;  }
        if (ix0 < -1 || ix0 > W_ - 1) { ea = 0.0f; eb = 0.0f; }

        // y validity (zeros padding); y clamp via staging row replication
        const float ey0 = ((unsigned)iy0       < (unsigned)H_) ? wy0 : 0.0f;
        const float ey1 = ((unsigned)(iy0 + 1) < (unsigned)H_) ? wy1 : 0.0f;

        w00[r] = ey0 * ea; w01[r] = ey0 * eb;
        w10[r] = ey1 * ea; w11[r] = ey1 * eb;

        const int base = min(max(ix0, 0), W_ - 2);   // 0..254
        const int brw  = iy0 - wlo;
        const int brwc = min(max(brw, 0), WMAXBR);   // 0..30
        badmask |= ((unsigned)brw > (unsigned)WMAXBR) ? (1u << r) : 0u;
        oidx[r] = brwc * W_ + base;
    }

    const bool anybad = __any(badmask != 0u);

    // ---- write window 0 (vmcnt waits only on f4) ----
#pragma unroll
    for (int it = 0; it < STV; ++it)
        *(float4*)(win + it * 1024 + tid * 4) = f4[it];

    // ---- channel loop: issue(ch+1) right AFTER the barrier, gather(ch),
    //      then barrier+ds_write (loads have a full gather to land) ----
#pragma unroll 1
    for (int ch = 0; ch < CG; ++ch) {
        __syncthreads();               // window ch visible to all waves

        if (ch + 1 < CG) {
#pragma unroll
            for (int it = 0; it < STV; ++it)
                f4[it] = *(const float4*)(frame + bc0 + (size_t)(ch + 1) * HW_ + soff[it]);
        }

        float* __restrict__ dst = out + bc0 + (size_t)ch * HW_ + spbase;

#pragma unroll
        for (int r = 0; r < BAND; ++r) {
            const int o = oidx[r];
            const float a  = win[o];
            const float bb = win[o + 1];
            const float cl = win[o + W_];
            const float dl = win[o + W_ + 1];
            const float v = w00[r] * a + w01[r] * bb + w10[r] * cl + w11[r] * dl;
            __builtin_nontemporal_store(v, dst + r * W_);
        }

        if (ch + 1 < CG) {
            __syncthreads();           // all window reads done
#pragma unroll
            for (int it = 0; it < STV; ++it)
                *(float4*)(win + it * 1024 + tid * 4) = f4[it];
        }
    }

    // ---- hoisted fixup: window-miss rows, global taps, all channels ----
    if (anybad) {
#pragma unroll 1
        for (int r = 0; r < BAND; ++r) {
            if ((badmask >> r) & 1u) {
                const int py = r0 + r;
                const float fxr = flx[spbase + r * W_];   // L2 hit
                const float fyr = fly[spbase + r * W_];

                const float ix = (float)px + 0.5f * fxr;
                const float iy = (float)py + 0.5f * fyr;

                const float ix0f = floorf(ix);
                const float iy0f = floorf(iy);
                const float wx1 = ix - ix0f;
                const float wx0 = 1.0f - wx1;
                const float wy1 = iy - iy0f;
                const float wy0 = 1.0f - wy1;

                const int ix0 = (int)ix0f;
                const int iy0 = (int)iy0f;

                const float wx0v = ((unsigned)ix0       < (unsigned)W_) ? wx0 : 0.0f;
                const float wx1v = ((unsigned)(ix0 + 1) < (unsigned)W_) ? wx1 : 0.0f;
                const float wy0v = ((unsigned)iy0       < (unsigned)H_) ? wy0 : 0.0f;
                const float wy1v = ((unsigned)(iy0 + 1) < (unsigned)H_) ? wy1 : 0.0f;

                const int xc0 = min(max(ix0, 0), W_ - 1);
                const int xc1 = min(max(ix0 + 1, 0), W_ - 1);
                const int yc0 = min(max(iy0, 0), H_ - 1);
                const int yc1 = min(max(iy0 + 1, 0), H_ - 1);

#pragma unroll
                for (int ch = 0; ch < CG; ++ch) {
                    const float* __restrict__ src = frame + bc0 + (size_t)ch * HW_;
                    const float t00 = src[yc0 * W_ + xc0];
                    const float t01 = src[yc0 * W_ + xc1];
                    const float t10 = src[yc1 * W_ + xc0];
                    const float t11 = src[yc1 * W_ + xc1];

                    const float h0 = wx0v * t00 + wx1v * t01;
                    const float h1 = wx0v * t10 + wx1v * t11;
                    const float v  = wy0v * h0 + wy1v * h1;

                    __builtin_nontemporal_store(v, out + bc0 + (size_t)ch * HW_ + spbase + r * W_);
                }
            }
        }
    }
}

extern "C" void kernel_launch(void* const* d_in, const int* in_sizes, int n_in,
                              void* d_out, int out_size, void* d_ws, size_t ws_size,
                              hipStream_t stream) {
    const float* frame = (const float*)d_in[0];
    const float* flow  = (const float*)d_in[1];
    float* out = (float*)d_out;

    dim3 grid(B_ * NBAND * (C_ / CG));  // 2048 blocks: (cg, band, b), b fastest
    dim3 block(256);
    warp_bilinear_kernel<<<grid, block, 0, stream>>>(frame, flow, out);
}

// Round 8
// 295.129 us; speedup vs baseline: 1.2808x; 1.2479x over previous
//
#include <hip/hip_runtime.h>

// Bilinear warp (grid_sample, zeros padding) of frame_t (8,64,256,256) fp32
// by flow_field (8,2,256,256) fp32.
//   ix = px + 0.5*flow_x ; iy = py + 0.5*flow_y   (normalization collapses)
//
// R11 — R10 bugfix. R10's two-kernel split was right (weights through
// global memory kills the scratch-spill that ate R7/R8/R9), but the
// window-miss encoding packed only yc0 and reconstructed yc1=min(yc0+1,255)
// — wrong for iy0<0, where clamp gives yc0=yc1=0. The ey1-weighted tap
// then read row 1 instead of row 0 -> absmax 2.02 on rare pixels. Fix:
// encode BOTH clamp rows: oi = bit31 | yc1<<16 | yc0<<8 | base.
//
//  kernel 1 (warp_weights): per pixel, R7-proven weight pipeline ONCE ->
//    float4{w00,w01,w10,w11} + packed oidx into d_ws (10.5 MB).
//    oidx >= 0 : LDS window offset (brw*256+base), taps in-window.
//    oidx <  0 : miss: bit31 | yc1<<16 | yc0<<8 | base (rows pre-clamped).
//  kernel 2 (warp_gather): block = (b, ch, 8-row band); 16384 blocks,
//    b fastest (XCD-local) then ch -> weight band stays L2-hot across the
//    64 channel-blocks; frame window re-reads absorbed by L3 (128 MB
//    frame < 256 MB L3). Stage 32-row window (32 KiB LDS, R5-proven
//    float4 path, y-clamp = row replication) -> per row: 1 float4 weight
//    load + 1 int load + 4 ds_read + 4 FMA + 1 nontemporal store.
//    No per-thread arrays, no mid-kernel barriers, 5 blocks/CU.
//  ws_size guard: falls back to the R5-proven single kernel (92 us).

#define B_ 8
#define C_ 64
#define H_ 256
#define W_ 256
#define HW_ (H_ * W_)
#define BAND 8
#define NBAND (H_ / BAND)              // 32
#define HALO 12
#define WROWS (BAND + 2 * HALO)        // 32 rows
#define WFLOATS (WROWS * W_)           // 8192 floats = 32 KiB
#define WMAXBR (WROWS - 2)             // 30: max base row (reads brw, brw+1)

// ======================= kernel 1: weights ==========================
__global__ __launch_bounds__(256) void warp_weights_kernel(
    const float* __restrict__ flow,    // (8,2,256,256)
    float4* __restrict__ w4,           // (8,256,256)
    int* __restrict__ wsi)             // (8,256,256)
{
    const int blk = blockIdx.x;        // 0..2047
    const int b   = blk >> 8;
    const int y   = blk & 255;
    const int x   = threadIdx.x;
    const int p   = y * W_ + x;

    const float fx = flow[(size_t)(b * 2 + 0) * HW_ + p];
    const float fy = flow[(size_t)(b * 2 + 1) * HW_ + p];

    const float ix = (float)x + 0.5f * fx;
    const float iy = (float)y + 0.5f * fy;

    const float ix0f = floorf(ix);
    const float iy0f = floorf(iy);
    const float wx1 = ix - ix0f;
    const float wx0 = 1.0f - wx1;
    const float wy1 = iy - iy0f;
    const float wy0 = 1.0f - wy1;

    const int ix0 = (int)ix0f;
    const int iy0 = (int)iy0f;

    // x edge-remap onto base=clamp(ix0,0,254) (R7-proven):
    //  ix0 in [0,254]: ea=wx0, eb=wx1
    //  ix0 == -1    : x1 tap (col 0) lands on a -> ea=wx1, eb=0
    //  ix0 == 255   : x0 tap (col 255) lands on b -> ea=0, eb=wx0
    //  else         : both invalid -> 0,0
    float ea = wx0, eb = wx1;
    if (ix0 == -1)                { ea = wx1;  eb = 0.0f; }
    if (ix0 == W_ - 1)            { ea = 0.0f; eb = wx0;  }
    if (ix0 < -1 || ix0 > W_ - 1) { ea = 0.0f; eb = 0.0f; }

    // y validity (zeros padding); in-window y clamp via staged replication
    const float ey0 = ((unsigned)iy0       < (unsigned)H_) ? wy0 : 0.0f;
    const float ey1 = ((unsigned)(iy0 + 1) < (unsigned)H_) ? wy1 : 0.0f;

    const int base = min(max(ix0, 0), W_ - 2);       // 0..254
    const int wlo  = (y & ~(BAND - 1)) - HALO;       // band window start
    const int brw  = iy0 - wlo;

    int oi;
    if ((unsigned)brw <= (unsigned)WMAXBR) {
        oi = brw * W_ + base;                        // in-window: LDS offset
    } else {
        // miss: encode BOTH clamped tap rows (independent clamps!)
        const int yc0 = min(max(iy0,     0), H_ - 1);
        const int yc1 = min(max(iy0 + 1, 0), H_ - 1);
        oi = (int)(0x80000000u | ((unsigned)yc1 << 16)
                               | ((unsigned)yc0 << 8) | (unsigned)base);
    }

    const size_t o = (size_t)b * HW_ + p;
    w4[o]  = make_float4(ey0 * ea, ey0 * eb, ey1 * ea, ey1 * eb);
    wsi[o] = oi;
}

// ======================= kernel 2: gather ===========================
__global__ __launch_bounds__(256, 5) void warp_gather_kernel(
    const float* __restrict__ frame,   // (8,64,256,256)
    const float4* __restrict__ w4,     // (8,256,256)
    const int* __restrict__ wsi,       // (8,256,256)
    float* __restrict__ out)           // (8,64,256,256)
{
    __shared__ float win[WFLOATS];

    const int blk  = blockIdx.x;
    const int b    = blk & 7;          // XCD-local batch
    const int ch   = (blk >> 3) & 63;  // next: weight band L2-hot over ch sweep
    const int band = blk >> 9;

    const int r0  = band * BAND;
    const int wlo = r0 - HALO;

    const int tid = threadIdx.x;       // 0..255 == pixel column
    const int px  = tid;

    const float* __restrict__ src = frame + ((size_t)(b * C_ + ch)) * HW_;

    // ---- stage 32 rows x 256 cols (R5-proven float4 path) ----
#pragma unroll
    for (int it = 0; it < WFLOATS / (256 * 4); ++it) {   // 8 iters
        const int lin = it * 1024 + tid * 4;
        const int wr  = lin >> 8;
        const int gy  = min(max(wlo + wr, 0), H_ - 1);   // y-clamp replication
        *(float4*)(win + lin) = *(const float4*)(src + gy * W_ + (lin & 255));
    }
    __syncthreads();

    const size_t wb = (size_t)b * HW_ + (size_t)r0 * W_ + px;
    float* __restrict__ dst = out + ((size_t)(b * C_ + ch)) * HW_ + r0 * W_ + px;

#pragma unroll
    for (int r = 0; r < BAND; ++r) {
        const float4 w = w4[wb + r * W_];
        const int   oi = wsi[wb + r * W_];

        float a, bb, cl, dl;
        if (oi >= 0) {
            a  = win[oi];
            bb = win[oi + 1];
            cl = win[oi + W_];
            dl = win[oi + W_ + 1];
        } else {
            const int basec = oi & 255;
            const int yc0   = (oi >> 8)  & 255;
            const int yc1   = (oi >> 16) & 255;
            a  = src[yc0 * W_ + basec];
            bb = src[yc0 * W_ + basec + 1];
            cl = src[yc1 * W_ + basec];
            dl = src[yc1 * W_ + basec + 1];
        }

        const float v = w.x * a + w.y * bb + w.z * cl + w.w * dl;
        __builtin_nontemporal_store(v, dst + r * W_);
    }
}

// ================= fallback: R5-proven fused kernel =================
#define FB_BAND 16
#define FB_NBAND (H_ / FB_BAND)
#define FB_WROWS (FB_BAND + 2 * HALO)      // 40
#define FB_WFLOATS (FB_WROWS * W_)         // 40 KiB
#define FB_WMAXBR (FB_WROWS - 2)

__global__ __launch_bounds__(256, 4) void warp_bilinear_fb(
    const float* __restrict__ frame, const float* __restrict__ flow,
    float* __restrict__ out)
{
    __shared__ float win[FB_WFLOATS];
    const int blk = blockIdx.x;
    const int b = blk & 7;
    const int t = blk >> 3;
    const int band = t & (FB_NBAND - 1);
    const int c = t >> 4;
    const int r0 = band * FB_BAND;
    const int wlo = r0 - HALO;
    const int tid = threadIdx.x;
    const int px = tid;
    const float* __restrict__ src = frame + ((size_t)(b * C_ + c)) * HW_;
#pragma unroll
    for (int it = 0; it < FB_WFLOATS / (256 * 4); ++it) {
        const int lin = it * 1024 + tid * 4;
        const int wr = lin >> 8;
        const int gy = min(max(wlo + wr, 0), H_ - 1);
        *(float4*)(win + lin) = *(const float4*)(src + gy * W_ + (lin & 255));
    }
    const int spbase = r0 * W_ + px;
    const float* __restrict__ flx = flow + (size_t)(b * 2 + 0) * HW_;
    const float* __restrict__ fly = flow + (size_t)(b * 2 + 1) * HW_;
    float fx[FB_BAND], fy[FB_BAND];
#pragma unroll
    for (int r = 0; r < FB_BAND; ++r) {
        fx[r] = flx[spbase + r * W_];
        fy[r] = fly[spbase + r * W_];
    }
    __syncthreads();
    float* __restrict__ dst = out + ((size_t)(b * C_ + c)) * HW_;
    unsigned badmask = 0u;
#pragma unroll
    for (int r = 0; r < FB_BAND; ++r) {
        const int py = r0 + r;
        const float ix = (float)px + 0.5f * fx[r];
        const float iy = (float)py + 0.5f * fy[r];
        const float ix0f = floorf(ix), iy0f = floorf(iy);
        const float wx1 = ix - ix0f, wx0 = 1.0f - wx1;
        const float wy1 = iy - iy0f, wy0 = 1.0f - wy1;
        const int ix0 = (int)ix0f, iy0 = (int)iy0f;
        const float wx0v = ((unsigned)ix0 < (unsigned)W_) ? wx0 : 0.0f;
        const float wx1v = ((unsigned)(ix0 + 1) < (unsigned)W_) ? wx1 : 0.0f;
        const float wy0v = ((unsigned)iy0 < (unsigned)H_) ? wy0 : 0.0f;
        const float wy1v = ((unsigned)(iy0 + 1) < (unsigned)H_) ? wy1 : 0.0f;
        const int base = min(max(ix0, 0), W_ - 2);
        const int bry = min(max(iy0, 0), H_ - 2);
        const int brw = bry - wlo;
        const int brwc = min(max(brw, 0), FB_WMAXBR);
        badmask |= ((unsigned)brw > (unsigned)FB_WMAXBR) ? (1u << r) : 0u;
        const int o0 = brwc * W_ + base;
        const float a = win[o0], bb = win[o0 + 1];
        const float cl = win[o0 + W_], dl = win[o0 + W_ + 1];
        const bool xhi = (ix0 >= W_ - 1), xlo = (ix0 < 0);
        const float rl0 = xhi ? bb : a, rh0 = xhi ? dl : cl;
        const float rl1 = xlo ? a : bb, rh1 = xlo ? cl : dl;
        const bool yhi = (iy0 >= H_ - 1), ylo = (iy0 < 0);
        const float t00 = yhi ? rh0 : rl0, t10 = ylo ? rl0 : rh0;
        const float t01 = yhi ? rh1 : rl1, t11 = ylo ? rl1 : rh1;
        const float v = (wx0v * t00 + wx1v * t01) * wy0v +
                        (wx0v * t10 + wx1v * t11) * wy1v;
        __builtin_nontemporal_store(v, dst + spbase + r * W_);
    }
    if (__any(badmask != 0u)) {
#pragma unroll 1
        for (int r = 0; r < FB_BAND; ++r) {
            if ((badmask >> r) & 1u) {
                const int py = r0 + r;
                const float ix = (float)px + 0.5f * fx[r];
                const float iy = (float)py + 0.5f * fy[r];
                const float ix0f = floorf(ix), iy0f = floorf(iy);
                const float wx1 = ix - ix0f, wx0 = 1.0f - wx1;
                const float wy1 = iy - iy0f, wy0 = 1.0f - wy1;
                const int ix0 = (int)ix0f, iy0 = (int)iy0f;
                const float wx0v = ((unsigned)ix0 < (unsigned)W_) ? wx0 : 0.0f;
                const float wx1v = ((unsigned)(ix0 + 1) < (unsigned)W_) ? wx1 : 0.0f;
                const float wy0v = ((unsigned)iy0 < (unsigned)H_) ? wy0 : 0.0f;
                const float wy1v = ((unsigned)(iy0 + 1) < (unsigned)H_) ? wy1 : 0.0f;
                const int xc0 = min(max(ix0, 0), W_ - 1);
                const int xc1 = min(max(ix0 + 1, 0), W_ - 1);
                const int yc0 = min(max(iy0, 0), H_ - 1);
                const int yc1 = min(max(iy0 + 1, 0), H_ - 1);
                const float v = wy0v * (wx0v * src[yc0 * W_ + xc0] + wx1v * src[yc0 * W_ + xc1])
                              + wy1v * (wx0v * src[yc1 * W_ + xc0] + wx1v * src[yc1 * W_ + xc1]);
                __builtin_nontemporal_store(v, dst + spbase + r * W_);
            }
        }
    }
}

extern "C" void kernel_launch(void* const* d_in, const int* in_sizes, int n_in,
                              void* d_out, int out_size, void* d_ws, size_t ws_size,
                              hipStream_t stream) {
    const float* frame = (const float*)d_in[0];
    const float* flow  = (const float*)d_in[1];
    float* out = (float*)d_out;

    const size_t nw4  = (size_t)B_ * HW_ * sizeof(float4);   // 8.4 MB
    const size_t nwsi = (size_t)B_ * HW_ * sizeof(int);      // 2.1 MB

    if (d_ws != nullptr && ws_size >= nw4 + nwsi) {
        float4* w4 = (float4*)d_ws;
        int*   wsi = (int*)((char*)d_ws + nw4);

        warp_weights_kernel<<<dim3(B_ * H_), dim3(256), 0, stream>>>(flow, w4, wsi);
        warp_gather_kernel<<<dim3(B_ * C_ * NBAND), dim3(256), 0, stream>>>(frame, w4, wsi, out);
    } else {
        warp_bilinear_fb<<<dim3(B_ * C_ * FB_NBAND), dim3(256), 0, stream>>>(frame, flow, out);
    }
}

// Round 9
// 257.250 us; speedup vs baseline: 1.4694x; 1.1472x over previous
//
#include <hip/hip_runtime.h>
#include <hip/hip_fp16.h>

// Bilinear warp (grid_sample, zeros padding) of frame_t (8,64,256,256) fp32
// by flow_field (8,2,256,256) fp32.
//   ix = px + 0.5*flow_x ; iy = py + 0.5*flow_y   (normalization collapses)
//
// R12 — synthesis of the R7..R11 arc:
//   R7/R8/R9: weight amortization in REGISTER arrays -> allocator refuses,
//             scratch spill (WRITE_SIZE 131->554 MB at VGPR 52).
//   R11:      weights in GLOBAL -> no spill, but 64x L2 re-read (~670 MB)
//             + doubled staging amplification -> 135 us, all pipes idle.
//   R12:      weights in LDS. Allocator-proof, read at LDS speed, computed
//             once per block and reused by 8 channels.
//  - Block = (b, 8-row band, 8-channel group); grid 8*32*8 = 2048.
//  - LDS: window 32 rows x 256 = 32 KB (halo 12 = 3 sigma)
//         + half2 weights 2x2048x4B = 16 KB (fp16 rounding <=0.01 abs,
//           threshold 0.089) + u16 tap offsets 4 KB  => 52 KB, 3 blocks/CU.
//  - Phase 1: R7-proven weight pipeline (x edge-remap onto clamped base,
//    y validity zeroing; y clamp via staged-row replication) -> LDS.
//    Window-miss lanes (|disp_y|>~12, ~0.6%/px): offset = 0xFFFF sentinel,
//    bit in scalar badmask reg; fixup recomputes exactly from flow with
//    global taps after each channel's row loop (R5-proven path).
//  - Channel loop: restage window (R5-proven float4 path, 8 iters), then
//    8 rows branchless: 3 LDS weight reads + 4 LDS taps + 4 FMA + 1
//    nontemporal store. No per-thread arrays anywhere.
//  - b in low 3 bits of blockIdx -> XCD-local; band next -> 24/32-row L2
//    overlap between adjacent blocks.
//
// Predicted: dur ~55-70 us, WRITE_SIZE ~131 MB & VGPR<=64 (no spill),
// VALUBusy 25-35%, FETCH ~70 MB, occupancy ~37%.

#define B_ 8
#define C_ 64
#define H_ 256
#define W_ 256
#define HW_ (H_ * W_)
#define BAND 8
#define NBAND (H_ / BAND)              // 32
#define HALO 12
#define WROWS (BAND + 2 * HALO)        // 32 rows
#define WFLOATS (WROWS * W_)           // 8192 floats = 32 KiB
#define WMAXBR (WROWS - 2)             // 30: max base row (reads brw, brw+1)
#define CG 8                           // channels per block
#define SENT 0xFFFFu

__global__ __launch_bounds__(256, 3) void warp_bilinear_kernel(
    const float* __restrict__ frame,   // (8,64,256,256)
    const float* __restrict__ flow,    // (8,2,256,256)
    float* __restrict__ out)           // (8,64,256,256)
{
    __shared__ float win[WFLOATS];                 // 32 KB
    __shared__ __half2 wh01[BAND * W_];            // 8 KB: w00,w01
    __shared__ __half2 wh23[BAND * W_];            // 8 KB: w10,w11
    __shared__ unsigned short ox[BAND * W_];       // 4 KB: LDS tap offset / SENT

    const int blk  = blockIdx.x;
    const int b    = blk & 7;          // XCD-local batch
    const int band = (blk >> 3) & (NBAND - 1);  // adjacent blocks overlap rows
    const int cg   = blk >> 8;         // 0..7
    const int c0   = cg * CG;

    const int r0  = band * BAND;
    const int wlo = r0 - HALO;         // first window row (may be <0)

    const int tid = threadIdx.x;       // 0..255 == pixel column
    const int px  = tid;

    const size_t bc0 = (size_t)(b * C_ + c0) * HW_;

    const int spbase = r0 * W_ + px;
    const float* __restrict__ flx = flow + (size_t)(b * 2 + 0) * HW_;
    const float* __restrict__ fly = flow + (size_t)(b * 2 + 1) * HW_;

    // ---- phase 1: weights + offsets ONCE for all CG channels -> LDS ----
    unsigned badmask = 0u;
#pragma unroll
    for (int r = 0; r < BAND; ++r) {
        const int p = spbase + r * W_;
        const float fx = flx[p];
        const float fy = fly[p];

        const float ix = (float)px + 0.5f * fx;
        const float iy = (float)(r0 + r) + 0.5f * fy;

        const float ix0f = floorf(ix);
        const float iy0f = floorf(iy);
        const float wx1 = ix - ix0f;
        const float wx0 = 1.0f - wx1;
        const float wy1 = iy - iy0f;
        const float wy0 = 1.0f - wy1;

        const int ix0 = (int)ix0f;
        const int iy0 = (int)iy0f;

        // x edge-remap onto base=clamp(ix0,0,254) (R7-proven):
        float ea = wx0, eb = wx1;
        if (ix0 == -1)                { ea = wx1;  eb = 0.0f; }
        if (ix0 == W_ - 1)            { ea = 0.0f; eb = wx0;  }
        if (ix0 < -1 || ix0 > W_ - 1) { ea = 0.0f; eb = 0.0f; }

        // y validity (zeros padding); y clamp via staged-row replication
        const float ey0 = ((unsigned)iy0       < (unsigned)H_) ? wy0 : 0.0f;
        const float ey1 = ((unsigned)(iy0 + 1) < (unsigned)H_) ? wy1 : 0.0f;

        const int base = min(max(ix0, 0), W_ - 2);   // 0..254
        const int brw  = iy0 - wlo;
        const bool inwin = (unsigned)brw <= (unsigned)WMAXBR;

        const int li = r * W_ + px;
        wh01[li] = __floats2half2_rn(ey0 * ea, ey0 * eb);
        wh23[li] = __floats2half2_rn(ey1 * ea, ey1 * eb);
        ox[li]   = inwin ? (unsigned short)(brw * W_ + base)
                         : (unsigned short)SENT;
        badmask |= inwin ? 0u : (1u << r);
    }
    const bool anybad = __any(badmask != 0u);

    // ---- stage window for channel 0 (R5-proven float4 path) ----
#pragma unroll
    for (int it = 0; it < WFLOATS / (256 * 4); ++it) {   // 8 iters
        const int lin = it * 1024 + tid * 4;
        const int wr  = lin >> 8;
        const int gy  = min(max(wlo + wr, 0), H_ - 1);   // y-clamp replication
        *(float4*)(win + lin) = *(const float4*)(frame + bc0 + gy * W_ + (lin & 255));
    }
    __syncthreads();

    // ---- channel loop: branchless gather from LDS weights + window ----
#pragma unroll 1
    for (int ch = 0; ch < CG; ++ch) {
        float* __restrict__ dst = out + bc0 + (size_t)ch * HW_ + spbase;

#pragma unroll
        for (int r = 0; r < BAND; ++r) {
            const int li = r * W_ + px;
            const int oi = min((int)ox[li], WMAXBR * W_ + W_ - 2); // SENT-safe
            const float2 w01 = __half22float2(wh01[li]);
            const float2 w23 = __half22float2(wh23[li]);

            const float a  = win[oi];
            const float bb = win[oi + 1];
            const float cl = win[oi + W_];
            const float dl = win[oi + W_ + 1];

            const float v = w01.x * a + w01.y * bb + w23.x * cl + w23.y * dl;
            __builtin_nontemporal_store(v, dst + r * W_);
        }

        // rare fixup: window-miss lanes, exact recompute + global taps
        if (anybad) {
            const float* __restrict__ src = frame + bc0 + (size_t)ch * HW_;
#pragma unroll 1
            for (int r = 0; r < BAND; ++r) {
                if ((badmask >> r) & 1u) {
                    const int p = spbase + r * W_;
                    const float fx = flx[p];
                    const float fy = fly[p];

                    const float ix = (float)px + 0.5f * fx;
                    const float iy = (float)(r0 + r) + 0.5f * fy;

                    const float ix0f = floorf(ix);
                    const float iy0f = floorf(iy);
                    const float wx1 = ix - ix0f;
                    const float wx0 = 1.0f - wx1;
                    const float wy1 = iy - iy0f;
                    const float wy0 = 1.0f - wy1;

                    const int ix0 = (int)ix0f;
                    const int iy0 = (int)iy0f;

                    const float wx0v = ((unsigned)ix0       < (unsigned)W_) ? wx0 : 0.0f;
                    const float wx1v = ((unsigned)(ix0 + 1) < (unsigned)W_) ? wx1 : 0.0f;
                    const float wy0v = ((unsigned)iy0       < (unsigned)H_) ? wy0 : 0.0f;
                    const float wy1v = ((unsigned)(iy0 + 1) < (unsigned)H_) ? wy1 : 0.0f;

                    const int xc0 = min(max(ix0, 0), W_ - 1);
                    const int xc1 = min(max(ix0 + 1, 0), W_ - 1);
                    const int yc0 = min(max(iy0, 0), H_ - 1);
                    const int yc1 = min(max(iy0 + 1, 0), H_ - 1);

                    const float v = wy0v * (wx0v * src[yc0 * W_ + xc0] + wx1v * src[yc0 * W_ + xc1])
                                  + wy1v * (wx0v * src[yc1 * W_ + xc0] + wx1v * src[yc1 * W_ + xc1]);
                    __builtin_nontemporal_store(v, dst + r * W_);
                }
            }
        }

        // restage window for next channel
        if (ch + 1 < CG) {
            __syncthreads();           // all window reads done
#pragma unroll
            for (int it = 0; it < WFLOATS / (256 * 4); ++it) {
                const int lin = it * 1024 + tid * 4;
                const int wr  = lin >> 8;
                const int gy  = min(max(wlo + wr, 0), H_ - 1);
                *(float4*)(win + lin) =
                    *(const float4*)(frame + bc0 + (size_t)(ch + 1) * HW_ + gy * W_ + (lin & 255));
            }
            __syncthreads();           // new window staged
        }
    }
}

extern "C" void kernel_launch(void* const* d_in, const int* in_sizes, int n_in,
                              void* d_out, int out_size, void* d_ws, size_t ws_size,
                              hipStream_t stream) {
    const float* frame = (const float*)d_in[0];
    const float* flow  = (const float*)d_in[1];
    float* out = (float*)d_out;

    dim3 grid(B_ * NBAND * (C_ / CG));  // 2048 blocks: (cg, band, b), b fastest
    dim3 block(256);
    warp_bilinear_kernel<<<grid, block, 0, stream>>>(frame, flow, out);
}

// Round 10
// 248.819 us; speedup vs baseline: 1.5191x; 1.0339x over previous
//
#include <hip/hip_runtime.h>
#include <hip/hip_fp16.h>

// Bilinear warp (grid_sample, zeros padding) of frame_t (8,64,256,256) fp32
// by flow_field (8,2,256,256) fp32.
//   ix = px + 0.5*flow_x ; iy = py + 0.5*flow_y   (normalization collapses)
//
// R13 — the weight-amortization arc concluded:
//   R7/8/9: weights in REGISTER arrays -> allocator spills (WRITE 554MB).
//   R11:    weights in GLOBAL, 20 B/px -> 64x L2 re-read dominates (135us).
//   R12:    weights in LDS -> +50% LDS-pipe traffic, occupancy 26% (99us).
//   R13:    weights in GLOBAL at 8 B/px. Records total 4 MB -> permanently
//           L2-resident (512 KB per XCD batch-slice); read COALESCED
//           (lane i -> record i). Gather keeps R5's proven geometry
//           (BAND=16, 40KB window, 4 blocks/CU, 16 waves/CU).
//
// Record factorization (verified case-by-case): output =
//   wyA*( a + wx'*(b-a) ) + wyB*( c + wx'*(d-c) ),  taps at base..base+1,
//   rows brw..brw+1 of the staged window.
//   interior : wx'=wx1, wyA=ey0, wyB=ey1
//   ix0==-1  : base=0,   wx'=0, wyA=ey0*wx1, wyB=ey1*wx1  (x1 tap on col 0)
//   ix0==255 : base=254, wx'=1, wyA=ey0*wx0, wyB=ey1*wx0  (x0 tap on col255)
//   x fully out: wyA=wyB=0
//   y validity (zeros pad) in ey0/ey1; y clamp via staged-row replication
//   (raw-iy0 brw: replicated window rows serve iy0 in [-12..-1]/[255..267]).
//   window miss (brw outside [0,38], ~0.6%/px): oidx=0xFFFF sentinel ->
//   badmask -> R5-proven exact fixup from flow with global taps.
//
// kernel 1 (rec): per pixel once: R7-proven weight pipeline -> ushort4
//   {oidx, half wx', half wyA, half wyB} (half rounding ~5e-4; R12 already
//   passed with fp16 weights at absmax 0.031 vs threshold 0.089).
// kernel 2 (gather): per row: 1 coalesced 8B record load (L2-hot) +
//   4 LDS taps + ~13 VALU + 1 nontemporal store. No per-thread arrays.
// ws guard: falls back to R5-proven fused kernel (92 us).

#define B_ 8
#define C_ 64
#define H_ 256
#define W_ 256
#define HW_ (H_ * W_)
#define BAND 16
#define NBAND (H_ / BAND)              // 16
#define HALO 12
#define WROWS (BAND + 2 * HALO)        // 40 rows
#define WFLOATS (WROWS * W_)           // 10240 floats = 40 KiB
#define WMAXBR (WROWS - 2)             // 38
#define SENT 0xFFFFu

// ======================= kernel 1: records ==========================
__global__ __launch_bounds__(256) void warp_rec_kernel(
    const float* __restrict__ flow,    // (8,2,256,256)
    ushort4* __restrict__ rec)         // (8,256,256)
{
    const int blk = blockIdx.x;        // 0..2047
    const int b   = blk >> 8;
    const int y   = blk & 255;
    const int x   = threadIdx.x;
    const int p   = y * W_ + x;

    const float fx = flow[(size_t)(b * 2 + 0) * HW_ + p];
    const float fy = flow[(size_t)(b * 2 + 1) * HW_ + p];

    const float ix = (float)x + 0.5f * fx;
    const float iy = (float)y + 0.5f * fy;

    const float ix0f = floorf(ix);
    const float iy0f = floorf(iy);
    const float wx1 = ix - ix0f;
    const float wx0 = 1.0f - wx1;
    const float wy1 = iy - iy0f;
    const float wy0 = 1.0f - wy1;

    const int ix0 = (int)ix0f;
    const int iy0 = (int)iy0f;

    // y validity (zeros padding); y clamp comes from staged-row replication
    const float ey0 = ((unsigned)iy0       < (unsigned)H_) ? wy0 : 0.0f;
    const float ey1 = ((unsigned)(iy0 + 1) < (unsigned)H_) ? wy1 : 0.0f;

    // x edge factorization onto base=clamp(ix0,0,254)
    float wxp, sx;                     // weights scale sx folded into wyA/wyB
    if (ix0 >= 0 && ix0 <= W_ - 2)      { wxp = wx1;  sx = 1.0f; }
    else if (ix0 == -1)                 { wxp = 0.0f; sx = wx1;  }
    else if (ix0 == W_ - 1)             { wxp = 1.0f; sx = wx0;  }
    else                                { wxp = 0.0f; sx = 0.0f; }

    const float wA = ey0 * sx;
    const float wB = ey1 * sx;

    const int base = min(max(ix0, 0), W_ - 2);       // 0..254
    const int wlo  = (y & ~(BAND - 1)) - HALO;       // band window start
    const int brw  = iy0 - wlo;                      // raw iy0 (replication)

    ushort4 q;
    q.x = ((unsigned)brw <= (unsigned)WMAXBR)
            ? (unsigned short)(brw * W_ + base) : (unsigned short)SENT;
    q.y = __half_as_ushort(__float2half_rn(wxp));
    q.z = __half_as_ushort(__float2half_rn(wA));
    q.w = __half_as_ushort(__float2half_rn(wB));

    rec[(size_t)b * HW_ + p] = q;
}

// ======================= kernel 2: gather ===========================
__global__ __launch_bounds__(256, 4) void warp_gather_kernel(
    const float* __restrict__ frame,   // (8,64,256,256)
    const ushort4* __restrict__ rec,   // (8,256,256) L2-resident (4 MB)
    const float* __restrict__ flow,    // (8,2,256,256) fixup only
    float* __restrict__ out)           // (8,64,256,256)
{
    __shared__ float win[WFLOATS];

    const int blk  = blockIdx.x;
    const int b    = blk & 7;          // XCD-local batch
    const int t    = blk >> 3;
    const int band = t & (NBAND - 1);  // 24/40-row L2 overlap between neighbors
    const int c    = t >> 4;

    const int r0  = band * BAND;
    const int wlo = r0 - HALO;

    const int tid = threadIdx.x;       // 0..255 == pixel column
    const int px  = tid;

    const float* __restrict__ src = frame + ((size_t)(b * C_ + c)) * HW_;

    // ---- stage 40 rows x 256 cols (R5-proven float4 path) ----
#pragma unroll
    for (int it = 0; it < WFLOATS / (256 * 4); ++it) {   // 10 iters
        const int lin = it * 1024 + tid * 4;
        const int wr  = lin >> 8;
        const int gy  = min(max(wlo + wr, 0), H_ - 1);   // y-clamp replication
        *(float4*)(win + lin) = *(const float4*)(src + gy * W_ + (lin & 255));
    }
    __syncthreads();

    const int spbase = r0 * W_ + px;
    const ushort4* __restrict__ rp = rec + (size_t)b * HW_ + spbase;
    float* __restrict__ dst = out + ((size_t)(b * C_ + c)) * HW_ + spbase;

    unsigned badmask = 0u;

#pragma unroll
    for (int r = 0; r < BAND; ++r) {
        const ushort4 q = rp[r * W_];                    // coalesced 8B, L2-hot

        const int oraw = (int)q.x;
        badmask |= (oraw == (int)SENT) ? (1u << r) : 0u;
        const int oi = min(oraw, WMAXBR * W_ + W_ - 2);  // sentinel-safe

        const float wxp = __half2float(__ushort_as_half(q.y));
        const float wA  = __half2float(__ushort_as_half(q.z));
        const float wB  = __half2float(__ushort_as_half(q.w));

        const float a  = win[oi];
        const float bb = win[oi + 1];
        const float cl = win[oi + W_];
        const float dl = win[oi + W_ + 1];

        const float h0 = a  + wxp * (bb - a);
        const float h1 = cl + wxp * (dl - cl);
        const float v  = wA * h0 + wB * h1;

        __builtin_nontemporal_store(v, dst + r * W_);
    }

    // ---- rare fixup: window-miss rows, exact recompute + global taps ----
    if (__any(badmask != 0u)) {
        const float* __restrict__ flx = flow + (size_t)(b * 2 + 0) * HW_;
        const float* __restrict__ fly = flow + (size_t)(b * 2 + 1) * HW_;
#pragma unroll 1
        for (int r = 0; r < BAND; ++r) {
            if ((badmask >> r) & 1u) {
                const int py = r0 + r;
                const float fx = flx[spbase + r * W_];
                const float fy = fly[spbase + r * W_];

                const float ix = (float)px + 0.5f * fx;
                const float iy = (float)py + 0.5f * fy;

                const float ix0f = floorf(ix), iy0f = floorf(iy);
                const float wx1 = ix - ix0f, wx0 = 1.0f - wx1;
                const float wy1 = iy - iy0f, wy0 = 1.0f - wy1;
                const int ix0 = (int)ix0f, iy0 = (int)iy0f;

                const float wx0v = ((unsigned)ix0       < (unsigned)W_) ? wx0 : 0.0f;
                const float wx1v = ((unsigned)(ix0 + 1) < (unsigned)W_) ? wx1 : 0.0f;
                const float wy0v = ((unsigned)iy0       < (unsigned)H_) ? wy0 : 0.0f;
                const float wy1v = ((unsigned)(iy0 + 1) < (unsigned)H_) ? wy1 : 0.0f;

                const int xc0 = min(max(ix0, 0), W_ - 1);
                const int xc1 = min(max(ix0 + 1, 0), W_ - 1);
                const int yc0 = min(max(iy0, 0), H_ - 1);
                const int yc1 = min(max(iy0 + 1, 0), H_ - 1);

                const float v = wy0v * (wx0v * src[yc0 * W_ + xc0] + wx1v * src[yc0 * W_ + xc1])
                              + wy1v * (wx0v * src[yc1 * W_ + xc0] + wx1v * src[yc1 * W_ + xc1]);
                __builtin_nontemporal_store(v, dst + r * W_);
            }
        }
    }
}

// ================= fallback: R5-proven fused kernel =================
__global__ __launch_bounds__(256, 4) void warp_bilinear_fb(
    const float* __restrict__ frame, const float* __restrict__ flow,
    float* __restrict__ out)
{
    __shared__ float win[WFLOATS];
    const int blk = blockIdx.x;
    const int b = blk & 7;
    const int t = blk >> 3;
    const int band = t & (NBAND - 1);
    const int c = t >> 4;
    const int r0 = band * BAND;
    const int wlo = r0 - HALO;
    const int tid = threadIdx.x;
    const int px = tid;
    const float* __restrict__ src = frame + ((size_t)(b * C_ + c)) * HW_;
#pragma unroll
    for (int it = 0; it < WFLOATS / (256 * 4); ++it) {
        const int lin = it * 1024 + tid * 4;
        const int wr = lin >> 8;
        const int gy = min(max(wlo + wr, 0), H_ - 1);
        *(float4*)(win + lin) = *(const float4*)(src + gy * W_ + (lin & 255));
    }
    const int spbase = r0 * W_ + px;
    const float* __restrict__ flx = flow + (size_t)(b * 2 + 0) * HW_;
    const float* __restrict__ fly = flow + (size_t)(b * 2 + 1) * HW_;
    float fx[BAND], fy[BAND];
#pragma unroll
    for (int r = 0; r < BAND; ++r) {
        fx[r] = flx[spbase + r * W_];
        fy[r] = fly[spbase + r * W_];
    }
    __syncthreads();
    float* __restrict__ dst = out + ((size_t)(b * C_ + c)) * HW_;
    unsigned badmask = 0u;
#pragma unroll
    for (int r = 0; r < BAND; ++r) {
        const int py = r0 + r;
        const float ix = (float)px + 0.5f * fx[r];
        const float iy = (float)py + 0.5f * fy[r];
        const float ix0f = floorf(ix), iy0f = floorf(iy);
        const float wx1 = ix - ix0f, wx0 = 1.0f - wx1;
        const float wy1 = iy - iy0f, wy0 = 1.0f - wy1;
        const int ix0 = (int)ix0f, iy0 = (int)iy0f;
        const float wx0v = ((unsigned)ix0 < (unsigned)W_) ? wx0 : 0.0f;
        const float wx1v = ((unsigned)(ix0 + 1) < (unsigned)W_) ? wx1 : 0.0f;
        const float wy0v = ((unsigned)iy0 < (unsigned)H_) ? wy0 : 0.0f;
        const float wy1v = ((unsigned)(iy0 + 1) < (unsigned)H_) ? wy1 : 0.0f;
        const int base = min(max(ix0, 0), W_ - 2);
        const int bry = min(max(iy0, 0), H_ - 2);
        const int brw = bry - wlo;
        const int brwc = min(max(brw, 0), WMAXBR);
        badmask |= ((unsigned)brw > (unsigned)WMAXBR) ? (1u << r) : 0u;
        const int o0 = brwc * W_ + base;
        const float a = win[o0], bb = win[o0 + 1];
        const float cl = win[o0 + W_], dl = win[o0 + W_ + 1];
        const bool xhi = (ix0 >= W_ - 1), xlo = (ix0 < 0);
        const float rl0 = xhi ? bb : a, rh0 = xhi ? dl : cl;
        const float rl1 = xlo ? a : bb, rh1 = xlo ? cl : dl;
        const bool yhi = (iy0 >= H_ - 1), ylo = (iy0 < 0);
        const float t00 = yhi ? rh0 : rl0, t10 = ylo ? rl0 : rh0;
        const float t01 = yhi ? rh1 : rl1, t11 = ylo ? rl1 : rh1;
        const float v = (wx0v * t00 + wx1v * t01) * wy0v +
                        (wx0v * t10 + wx1v * t11) * wy1v;
        __builtin_nontemporal_store(v, dst + spbase + r * W_);
    }
    if (__any(badmask != 0u)) {
#pragma unroll 1
        for (int r = 0; r < BAND; ++r) {
            if ((badmask >> r) & 1u) {
                const int py = r0 + r;
                const float ix = (float)px + 0.5f * fx[r];
                const float iy = (float)py + 0.5f * fy[r];
                const float ix0f = floorf(ix), iy0f = floorf(iy);
                const float wx1 = ix - ix0f, wx0 = 1.0f - wx1;
                const float wy1 = iy - iy0f, wy0 = 1.0f - wy1;
                const int ix0 = (int)ix0f, iy0 = (int)iy0f;
                const float wx0v = ((unsigned)ix0 < (unsigned)W_) ? wx0 : 0.0f;
                const float wx1v = ((unsigned)(ix0 + 1) < (unsigned)W_) ? wx1 : 0.0f;
                const float wy0v = ((unsigned)iy0 < (unsigned)H_) ? wy0 : 0.0f;
                const float wy1v = ((unsigned)(iy0 + 1) < (unsigned)H_) ? wy1 : 0.0f;
                const int xc0 = min(max(ix0, 0), W_ - 1);
                const int xc1 = min(max(ix0 + 1, 0), W_ - 1);
                const int yc0 = min(max(iy0, 0), H_ - 1);
                const int yc1 = min(max(iy0 + 1, 0), H_ - 1);
                const float v = wy0v * (wx0v * src[yc0 * W_ + xc0] + wx1v * src[yc0 * W_ + xc1])
                              + wy1v * (wx0v * src[yc1 * W_ + xc0] + wx1v * src[yc1 * W_ + xc1]);
                __builtin_nontemporal_store(v, dst + spbase + r * W_);
            }
        }
    }
}

extern "C" void kernel_launch(void* const* d_in, const int* in_sizes, int n_in,
                              void* d_out, int out_size, void* d_ws, size_t ws_size,
                              hipStream_t stream) {
    const float* frame = (const float*)d_in[0];
    const float* flow  = (const float*)d_in[1];
    float* out = (float*)d_out;

    const size_t nrec = (size_t)B_ * HW_ * sizeof(ushort4);   // 4 MB

    if (d_ws != nullptr && ws_size >= nrec) {
        ushort4* rec = (ushort4*)d_ws;
        warp_rec_kernel<<<dim3(B_ * H_), dim3(256), 0, stream>>>(flow, rec);
        warp_gather_kernel<<<dim3(B_ * C_ * NBAND), dim3(256), 0, stream>>>(frame, rec, flow, out);
    } else {
        warp_bilinear_fb<<<dim3(B_ * C_ * NBAND), dim3(256), 0, stream>>>(frame, flow, out);
    }
}